// Round 10
// baseline (1010.989 us; speedup 1.0000x reference)
//
#include <hip/hip_runtime.h>
#include <hip/hip_bf16.h>

typedef __bf16 bf16;
typedef bf16 bf16x8 __attribute__((ext_vector_type(8)));
typedef float f32x4 __attribute__((ext_vector_type(4)));

__device__ __forceinline__ void glds16(const void* g, void* l) {
    __builtin_amdgcn_global_load_lds(
        (const __attribute__((address_space(1))) void*)g,
        (__attribute__((address_space(3))) void*)l, 16, 0, 0);
}

__device__ __forceinline__ float sigm(float x) { return 1.0f / (1.0f + __expf(-x)); }
__device__ __forceinline__ float tanh_f(float x) { return 2.0f / (1.0f + __expf(-2.0f * x)) - 1.0f; }

// ---------------------------------------------------------------------------
// fp32 -> bf16 conversion of x + 11 matrices into one packed ws area.
// ---------------------------------------------------------------------------
struct Cvt11 { const float* src[11]; unsigned gcnt[11]; };  // gcnt = elems/8

__global__ __launch_bounds__(256) void cvt_all(Cvt11 a, bf16* __restrict__ dst,
                                               unsigned total_g) {
    unsigned g = blockIdx.x * 256 + threadIdx.x;
    if (g >= total_g) return;
    unsigned s = 0, base = 0;
    while (g >= base + a.gcnt[s]) { base += a.gcnt[s]; ++s; }
    const float* sp = a.src[s] + (size_t)(g - base) * 8;
    float4 v0 = ((const float4*)sp)[0];
    float4 v1 = ((const float4*)sp)[1];
    bf16x8 o;
    o[0] = (bf16)v0.x; o[1] = (bf16)v0.y; o[2] = (bf16)v0.z; o[3] = (bf16)v0.w;
    o[4] = (bf16)v1.x; o[5] = (bf16)v1.y; o[6] = (bf16)v1.z; o[7] = (bf16)v1.w;
    *(bf16x8*)(dst + (size_t)g * 8) = o;
}

// Pack WcP[oct=68][2048][8]: oct o holds k-cols o*8..o*8+7 of
// Wcomb[2048,544] = Whh[2048,512] || Wih[2048,16] || zeros[16], bf16.
__global__ __launch_bounds__(128) void pack_w(const float* __restrict__ Whh,
                                              const float* __restrict__ Wih,
                                              bf16* __restrict__ WcP) {
    int row = blockIdx.x, seg = threadIdx.x;
    if (seg >= 68) return;
    bf16x8 o = {};
    if (seg < 64) {
        const float* sp = Whh + (size_t)row * 512 + seg * 8;
        float4 v0 = ((const float4*)sp)[0];
        float4 v1 = ((const float4*)sp)[1];
        o[0]=(bf16)v0.x; o[1]=(bf16)v0.y; o[2]=(bf16)v0.z; o[3]=(bf16)v0.w;
        o[4]=(bf16)v1.x; o[5]=(bf16)v1.y; o[6]=(bf16)v1.z; o[7]=(bf16)v1.w;
    } else if (seg < 66) {
        const float* sp = Wih + (size_t)row * 16 + (seg - 64) * 8;
        float4 v0 = ((const float4*)sp)[0];
        float4 v1 = ((const float4*)sp)[1];
        o[0]=(bf16)v0.x; o[1]=(bf16)v0.y; o[2]=(bf16)v0.z; o[3]=(bf16)v0.w;
        o[4]=(bf16)v1.x; o[5]=(bf16)v1.y; o[6]=(bf16)v1.z; o[7]=(bf16)v1.w;
    }
    *(bf16x8*)(WcP + ((size_t)seg * 2048 + row) * 8) = o;
}

// ---------------------------------------------------------------------------
// GEMM: C[M,N](ldc) = act(A[M,K] @ W[N,K]^T + bias).  (prologue, verified)
// ---------------------------------------------------------------------------
template <int ACT, typename OutT>
__global__ __launch_bounds__(256) void gemm_bt(
    const bf16* __restrict__ A, const bf16* __restrict__ W,
    const float* __restrict__ bias, OutT* __restrict__ C,
    int M, int N, int K, int ldc)
{
    __shared__ __attribute__((aligned(16))) bf16 sA[64 * 32];
    __shared__ __attribute__((aligned(16))) bf16 sB[128 * 32];
    const int t = threadIdx.x;
    const int lane = t & 63, w = t >> 6;
    const int wm = w >> 1, wn = w & 1;
    const int quad = lane >> 4, l16 = lane & 15;
    const int m0 = blockIdx.y * 64, n0 = blockIdx.x * 128;

    f32x4 acc[2][4] = {};
    const int nk = K >> 5;
    for (int kc = 0; kc < nk; ++kc) {
        const int k0 = kc << 5;
        if (kc) __syncthreads();
        {
            int row = t >> 2, kof = (t & 3) << 3;
            glds16(A + (size_t)(m0 + row) * K + k0 + kof, (char*)sA + (w << 10));
        }
        for (int i = 0; i < 2; ++i) {
            int gi = (i << 8) + t;
            int row = gi >> 2, kof = (gi & 3) << 3;
            glds16(W + (size_t)(n0 + row) * K + k0 + kof,
                   (char*)sB + (i << 12) + (w << 10));
        }
        __syncthreads();
        bf16x8 af[2], bfr[4];
        for (int mi = 0; mi < 2; ++mi)
            af[mi] = *(const bf16x8*)(sA + ((wm * 32 + mi * 16 + l16) * 32 + quad * 8));
        for (int ni = 0; ni < 4; ++ni)
            bfr[ni] = *(const bf16x8*)(sB + ((wn * 64 + ni * 16 + l16) * 32 + quad * 8));
        for (int mi = 0; mi < 2; ++mi)
            for (int ni = 0; ni < 4; ++ni)
                acc[mi][ni] = __builtin_amdgcn_mfma_f32_16x16x32_bf16(
                    af[mi], bfr[ni], acc[mi][ni], 0, 0, 0);
    }
    for (int mi = 0; mi < 2; ++mi) {
        for (int ni = 0; ni < 4; ++ni) {
            int gn = n0 + wn * 64 + ni * 16 + l16;
            float bv = bias[gn];
            for (int r = 0; r < 4; ++r) {
                int gm = m0 + wm * 32 + mi * 16 + quad * 4 + r;
                float v = acc[mi][ni][r] + bv;
                if (ACT) v = v >= 0.f ? v : 0.2f * v;
                C[(size_t)gm * ldc + gn] = (OutT)v;
            }
        }
    }
}

// ---------------------------------------------------------------------------
// MFMA head (used once, for x0): writes softmax/sigmoid into xt0[4096][16].
// ---------------------------------------------------------------------------
__global__ __launch_bounds__(256) void head_mfma(
    const bf16* __restrict__ A, int lda,
    const bf16* __restrict__ Wp16,
    const float* __restrict__ bias,
    bf16* __restrict__ xt_dst, int ldx)
{
    const int t = threadIdx.x;
    const int lane = t & 63, w = t >> 6;
    const int quad = lane >> 4, l16 = lane & 15;
    const int r0 = blockIdx.x * 64 + w * 16;
    f32x4 acc = {};
    for (int kk = 0; kk < 16; ++kk) {
        bf16x8 a = *(const bf16x8*)(A + (size_t)(r0 + l16) * lda + kk * 32 + quad * 8);
        bf16x8 b = *(const bf16x8*)(Wp16 + (size_t)l16 * 512 + kk * 32 + quad * 8);
        acc = __builtin_amdgcn_mfma_f32_16x16x32_bf16(a, b, acc, 0, 0, 0);
    }
    const int n = l16;
    const float bv = bias[n];
    for (int r = 0; r < 4; ++r) {
        float p = acc[r] + bv;
        float vmax = (n == 15) ? -3.0e38f : p;
        for (int m = 1; m < 16; m <<= 1) vmax = fmaxf(vmax, __shfl_xor(vmax, m));
        float e = (n == 15) ? 0.f : __expf(p - vmax);
        float s = e;
        for (int m = 1; m < 16; m <<= 1) s += __shfl_xor(s, m);
        float res = (n == 15) ? sigm(p) : e / s;
        int gr = r0 + quad * 4 + r;
        xt_dst[(size_t)gr * ldx + n] = (bf16)res;
    }
}

// ---------------------------------------------------------------------------
// lstm_solo32 v2: 128 independent blocks x 32 rows x all 512 units, 512
// threads (8 waves = 2/SIMD).  R9 structure + DEPTH-4 register prefetch
// (ring-5, kc%5 compile-time) so steady-state load->use distance ~= L2
// latency, + de-serialized head chain (4 independent pac accumulators).
// No inter-block communication of any kind.
// ---------------------------------------------------------------------------
__global__ __launch_bounds__(512, 1) void lstm_solo32(
    const bf16* __restrict__ h0g,   // [4096,512] h0 (prologue GEMM)
    const bf16* __restrict__ xt0,   // [4096,16]  x0-head (prologue)
    const bf16* __restrict__ WcP,   // [68][2048][8] oct-packed
    const bf16* __restrict__ Wp,    // [16,512]
    const float* __restrict__ bih, const float* __restrict__ bhh,
    const float* __restrict__ bp,
    const float* __restrict__ cb,   // [4096,512] fp32 c0
    float* __restrict__ outp)       // [4096,512] = [B, T*16]
{
    __shared__ __attribute__((aligned(16))) bf16 sH[2][32][552];  // 69 KB
    __shared__ float sC[32 * 516];                                // 64.5 KB
    __shared__ float sBias[2048];                                 // 8 KB
    const int t = threadIdx.x;
    const int lane = t & 63, w = t >> 6;         // 8 waves
    const int quad = lane >> 4, l16 = lane & 15;
    const int m0 = blockIdx.x * 32;

    // ---- one-time init ----
    for (int i = 0; i < 4; ++i)                       // sBias = bih + bhh
        sBias[i * 512 + t] = bih[i * 512 + t] + bhh[i * 512 + t];
#pragma unroll
    for (int i = 0; i < 8; ++i) {                     // sC <- c0 (32x512 f32)
        int idx = i * 512 + t;                        // 4096 float4 slots
        int row = idx >> 7, c4 = idx & 127;
        *(float4*)&sC[row * 516 + c4 * 4] =
            *(const float4*)(cb + (size_t)(m0 + row) * 512 + c4 * 4);
    }
    for (int i = 0; i < 5; ++i) {                     // sH[0] <- h0 || xt0 || 0
        int idx = i * 512 + t;                        // 32 rows x 68 col8
        if (idx < 2176) {
            int row = idx / 68, c8 = idx % 68, col = c8 * 8;
            bf16x8 v = {};
            if (col < 512)
                v = *(const bf16x8*)(h0g + (size_t)(m0 + row) * 512 + col);
            else if (col < 528)
                v = *(const bf16x8*)(xt0 + (size_t)(m0 + row) * 16 + (col - 512));
            *(bf16x8*)&sH[0][row][col] = v;
            if (col >= 528) *(bf16x8*)&sH[1][row][col] = v;  // zeros forever
        }
    }

    // lane-constant pieces: wave w owns units uw = w*16+l16 of each 128-group
    const int uw = w * 16 + l16;
    const bf16* bb = WcP + (size_t)quad * 16384 + (size_t)uw * 8;
    const float bp_l = bp[l16];
    __syncthreads();

#pragma unroll 1
    for (int st = 0; st <= 32; ++st) {
        const int hc = st & 1, hn = hc ^ 1;

        // ---- phase A (waves 0,1): xt_st = head(h_st @ Wp^T) = ys[st-1] ----
        if (st > 0 && w < 2) {
            f32x4 pc[4] = {};                 // 4 independent chains
#pragma unroll
            for (int kc = 0; kc < 16; ++kc) {
                bf16x8 af = *(const bf16x8*)&sH[hc][w * 16 + l16][kc * 32 + quad * 8];
                bf16x8 wpf = *(const bf16x8*)(Wp + (size_t)l16 * 512 +
                                              kc * 32 + quad * 8);
                pc[kc & 3] = __builtin_amdgcn_mfma_f32_16x16x32_bf16(
                    af, wpf, pc[kc & 3], 0, 0, 0);
            }
            f32x4 pac = (pc[0] + pc[1]) + (pc[2] + pc[3]);
#pragma unroll
            for (int r = 0; r < 4; ++r) {
                float pv = pac[r] + bp_l;
                float vmax = (l16 == 15) ? -3.0e38f : pv;
                for (int m = 1; m < 16; m <<= 1)
                    vmax = fmaxf(vmax, __shfl_xor(vmax, m));
                float e = (l16 == 15) ? 0.f : __expf(pv - vmax);
                float s = e;
                for (int m = 1; m < 16; m <<= 1) s += __shfl_xor(s, m);
                float res = (l16 == 15) ? sigm(pv) : e / s;
                int row = w * 16 + quad * 4 + r;
                if (st != 32) sH[hc][row][512 + l16] = (bf16)res;
                outp[(size_t)(m0 + row) * 512 + (st - 1) * 16 + l16] = res;
            }
        }
        __syncthreads();
        if (st == 32) break;

        // ---- main GEMM: 4 groups of 128 units (x4 gates), K = 17 chunks,
        //      depth-4 prefetch ring (slots = kc%5, compile-time) ----
#pragma unroll 1
        for (int nt = 0; nt < 4; ++nt) {
            const bf16* bnt = bb + (size_t)nt * 1024;   // +128 units
            f32x4 acc[2][4] = {};                        // [row-tile][gate]
            bf16x8 bfr[5][4];                            // ring-5, depth-4
#pragma unroll
            for (int pk = 0; pk < 4; ++pk)               // prime kc=0..3
#pragma unroll
                for (int ni = 0; ni < 4; ++ni)
                    bfr[pk][ni] = *(const bf16x8*)
                        (bnt + (size_t)ni * 4096 + (size_t)pk * 65536);
#pragma unroll
            for (int kc = 0; kc < 17; ++kc) {
                if (kc < 13) {
#pragma unroll
                    for (int ni = 0; ni < 4; ++ni)
                        bfr[(kc + 4) % 5][ni] = *(const bf16x8*)
                            (bnt + (size_t)ni * 4096 + (size_t)(kc + 4) * 65536);
                }
                bf16x8 af0 = *(const bf16x8*)&sH[hc][l16][kc * 32 + quad * 8];
                bf16x8 af1 = *(const bf16x8*)&sH[hc][16 + l16][kc * 32 + quad * 8];
#pragma unroll
                for (int ni = 0; ni < 4; ++ni) {
                    acc[0][ni] = __builtin_amdgcn_mfma_f32_16x16x32_bf16(
                        af0, bfr[kc % 5][ni], acc[0][ni], 0, 0, 0);
                    acc[1][ni] = __builtin_amdgcn_mfma_f32_16x16x32_bf16(
                        af1, bfr[kc % 5][ni], acc[1][ni], 0, 0, 0);
                }
            }
            // epilogue for these 128 units: gates -> c (LDS) -> h (LDS)
            const int u = nt * 128 + uw;
#pragma unroll
            for (int mi = 0; mi < 2; ++mi) {
#pragma unroll
                for (int r = 0; r < 4; ++r) {
                    int row = mi * 16 + quad * 4 + r;
                    float i_ = sigm(acc[mi][0][r] + sBias[u]);
                    float f_ = sigm(acc[mi][1][r] + sBias[512 + u]);
                    float g_ = tanh_f(acc[mi][2][r] + sBias[1024 + u]);
                    float o_ = sigm(acc[mi][3][r] + sBias[1536 + u]);
                    int ci = row * 516 + u;
                    float cn = f_ * sC[ci] + i_ * g_;
                    sC[ci] = cn;
                    sH[hn][row][u] = (bf16)(o_ * tanh_f(cn));
                }
            }
        }
        __syncthreads();   // h_{st+1} complete; all sH[hc] reads done
    }
}

// ---------------------------------------------------------------------------
extern "C" void kernel_launch(void* const* d_in, const int* in_sizes, int n_in,
                              void* d_out, int out_size, void* d_ws, size_t ws_size,
                              hipStream_t stream) {
    const float* xf   = (const float*)d_in[0];
    const float* W1f  = (const float*)d_in[1];  const float* b1  = (const float*)d_in[2];
    const float* W2f  = (const float*)d_in[3];  const float* b2  = (const float*)d_in[4];
    const float* W3f  = (const float*)d_in[5];  const float* b3  = (const float*)d_in[6];
    const float* Wh1f = (const float*)d_in[7];  const float* bh1 = (const float*)d_in[8];
    const float* Wh2f = (const float*)d_in[9];  const float* bh2 = (const float*)d_in[10];
    const float* Wc1f = (const float*)d_in[11]; const float* bc1 = (const float*)d_in[12];
    const float* Wc2f = (const float*)d_in[13]; const float* bc2 = (const float*)d_in[14];
    const float* Wx1f = (const float*)d_in[15]; const float* bx1 = (const float*)d_in[16];
    const float* Wx2f = (const float*)d_in[17]; const float* bx2 = (const float*)d_in[18];
    const float* Wihf = (const float*)d_in[19]; const float* bih = (const float*)d_in[20];
    const float* Whhf = (const float*)d_in[21]; const float* bhh = (const float*)d_in[22];
    const float* Wpf  = (const float*)d_in[23]; const float* bp  = (const float*)d_in[24];
    float* out = (float*)d_out;
    char* ws = (char*)d_ws;

    // layout (bytes): bufA 0..4456448 | bufB ..8650752 | hb0 ..13107200 |
    // cb ..21495808 | WcP ..23724032 | cvt ..28606464
    bf16*  bufA = (bf16*)(ws + 0);
    bf16*  bufB = (bf16*)(ws + 4456448);
    bf16*  hb0  = (bf16*)(ws + 8650752);      // [4096,512]
    float* cb   = (float*)(ws + 13107200);    // [4096,512] fp32
    bf16*  WcP  = (bf16*)(ws + 21495808);     // [68][2048][8]
    bf16*  cvt  = (bf16*)(ws + 23724032);     // packed bf16 weights

    const unsigned Ns[11] = {
        4096u * 128u,  // x
        512u * 128u,   // W1
        512u * 512u, 512u * 512u, 512u * 512u, 512u * 512u,  // W2,W3,Wh1,Wh2
        512u * 512u, 512u * 512u, 512u * 512u,               // Wc1,Wc2,Wx1
        16u * 512u,    // Wx2
        16u * 512u     // Wp
    };
    const float* srcs[11] = { xf, W1f, W2f, W3f, Wh1f, Wh2f, Wc1f, Wc2f,
                              Wx1f, Wx2f, Wpf };
    Cvt11 ca;
    unsigned off[12]; off[0] = 0;
    for (int i = 0; i < 11; ++i) {
        ca.src[i] = srcs[i];
        ca.gcnt[i] = Ns[i] >> 3;
        off[i + 1] = off[i] + Ns[i];
    }
    unsigned total_g = off[11] >> 3;
    cvt_all<<<dim3((total_g + 255) / 256), dim3(256), 0, stream>>>(ca, cvt, total_g);
    pack_w<<<dim3(2048), dim3(128), 0, stream>>>(Whhf, Wihf, WcP);

    const bf16* xb   = cvt + off[0];
    const bf16* W1b  = cvt + off[1];
    const bf16* W2b  = cvt + off[2];
    const bf16* W3b  = cvt + off[3];
    const bf16* Wh1b = cvt + off[4];
    const bf16* Wh2b = cvt + off[5];
    const bf16* Wc1b = cvt + off[6];
    const bf16* Wc2b = cvt + off[7];
    const bf16* Wx1b = cvt + off[8];
    const bf16* Wx2b = cvt + off[9];
    const bf16* Wpb  = cvt + off[10];
    // xt0 aliases the dead x slot (x only used by the first GEMM)
    bf16* xt0 = cvt + off[0];

    dim3 blk(256);
    dim3 gg(4, 64);  // N/128 x M/64
    gemm_bt<1, bf16 ><<<gg, blk, 0, stream>>>(xb,   W1b,  b1,  bufA, 4096, 512, 128, 512);
    gemm_bt<1, bf16 ><<<gg, blk, 0, stream>>>(bufA, W2b,  b2,  bufB, 4096, 512, 512, 512);
    gemm_bt<1, bf16 ><<<gg, blk, 0, stream>>>(bufB, W3b,  b3,  bufA, 4096, 512, 512, 512);
    gemm_bt<1, bf16 ><<<gg, blk, 0, stream>>>(bufA, Wh1b, bh1, bufB, 4096, 512, 512, 512);
    gemm_bt<0, bf16 ><<<gg, blk, 0, stream>>>(bufB, Wh2b, bh2, hb0,  4096, 512, 512, 512);
    gemm_bt<1, bf16 ><<<gg, blk, 0, stream>>>(bufA, Wc1b, bc1, bufB, 4096, 512, 512, 512);
    gemm_bt<0, float><<<gg, blk, 0, stream>>>(bufB, Wc2b, bc2, cb,   4096, 512, 512, 512);
    gemm_bt<1, bf16 ><<<gg, blk, 0, stream>>>(bufA, Wx1b, bx1, bufB, 4096, 512, 512, 512);
    head_mfma<<<dim3(64), blk, 0, stream>>>(bufB, 512, Wx2b, bx2, xt0, 16);

    // 128 independent per-CU recurrences; no inter-block communication
    lstm_solo32<<<dim3(128), dim3(512), 0, stream>>>(hb0, xt0, WcP, Wpb,
                                                     bih, bhh, bp, cb, out);
}